// Round 3
// baseline (17.459 us; speedup 1.0000x reference)
//
#include <hip/hip_runtime.h>

#define NN 65536
#define KK 8

// ws layout: ws[0..7] = A_i = sum_j W[i,1+j]
//            ws[8..15] = B_i = sum_j (j+1)*W[i,65+j]
//            ws[16..23] = C_i = W[i,0] + b[i]
__global__ void hermite_setup_kernel(const float* __restrict__ W,
                                     const float* __restrict__ b,
                                     float* __restrict__ ws) {
    int i = threadIdx.x >> 6;   // wave id == Hermite output index, 8 waves
    int j = threadIdx.x & 63;   // lane
    const float* Wi = W + i * 129;
    float a  = Wi[1 + j];
    float bb = (float)(j + 1) * Wi[65 + j];
    #pragma unroll
    for (int off = 32; off > 0; off >>= 1) {
        a  += __shfl_down(a, off, 64);
        bb += __shfl_down(bb, off, 64);
    }
    if (j == 0) {
        ws[i]          = a;
        ws[KK + i]     = bb;
        ws[2 * KK + i] = Wi[0] + b[i];
    }
}

__global__ void __launch_bounds__(256)
hermite_main_kernel(const float* __restrict__ e,
                    const float* __restrict__ scale,
                    const float* __restrict__ ws,
                    float* __restrict__ out) {
    int gid = blockIdx.x * 256 + threadIdx.x;
    int i = gid >> 16;          // output row 0..7 (wave-uniform)
    int n = gid & (NN - 1);     // element index

    float u = e[n];
    float s = scale[0];

    // p = u^(i+1)  (wave-uniform trip count, no divergence)
    float p = u;
    for (int k = 0; k < i; ++k) p *= u;

    float sp = s * p;
    // exp(-0.5*(sp*j)^2) = exp2(c * j^2), c = -0.5*log2(e)*sp^2
    float c = -0.5f * 1.44269504088896340736f * sp * sp;

    float acc = 0.0f;
    #pragma unroll
    for (int j = 1; j <= 64; ++j) {
        acc += exp2f(c * (float)(j * j));   // j*j is a compile-time constant
    }
    float gw = acc * (1.0f / 64.0f);

    float A = ws[i];
    float B = ws[KK + i];
    float C = ws[2 * KK + i];

    out[gid] = C + gw * (A + 2.0f * sp * B);
}

extern "C" void kernel_launch(void* const* d_in, const int* in_sizes, int n_in,
                              void* d_out, int out_size, void* d_ws, size_t ws_size,
                              hipStream_t stream) {
    const float* e     = (const float*)d_in[0];
    const float* W     = (const float*)d_in[1];
    const float* b     = (const float*)d_in[2];
    const float* scale = (const float*)d_in[3];
    float* out = (float*)d_out;
    float* ws  = (float*)d_ws;

    hermite_setup_kernel<<<1, 512, 0, stream>>>(W, b, ws);

    int total = KK * NN;                       // 524288 threads, one per output
    hermite_main_kernel<<<total / 256, 256, 0, stream>>>(e, scale, ws, out);
}

// Round 4
// 13.198 us; speedup vs baseline: 1.3228x; 1.3228x over previous
//
#include <hip/hip_runtime.h>

#define NN 65536
#define KK 8

// Single fused kernel: out[i*NN+n] = C_i + gw(n,i) * (A_i + 2*s*e[n]^(i+1)*B_i)
//   A_i = sum_j W[i,1+j]            (j=0..63)
//   B_i = sum_j (j+1)*W[i,65+j]
//   C_i = W[i,0] + b[i]
//   gw  = (1/64) * sum_{j=1..64} exp(-0.5*(s*e^(i+1)*j)^2)
// Only H0=1 and H1=2x survive bases[:, :HIDDEN] in the reference.
__global__ void __launch_bounds__(256)
hermite_fused_kernel(const float* __restrict__ e,
                     const float* __restrict__ W,
                     const float* __restrict__ b,
                     const float* __restrict__ scale,
                     float* __restrict__ out) {
    int gid  = blockIdx.x * 256 + threadIdx.x;
    int i    = gid >> 16;          // output row 0..7 (block-uniform)
    int n    = gid & (NN - 1);     // element index
    int lane = threadIdx.x & 63;

    // Per-wave recompute of A_i, B_i (butterfly so every lane holds the sum).
    // W row is L2-resident: 256 blocks per i re-read the same 516 B.
    const float* Wi = W + i * 129;
    float A = Wi[1 + lane];
    float B = (float)(lane + 1) * Wi[65 + lane];
    #pragma unroll
    for (int off = 1; off < 64; off <<= 1) {
        A += __shfl_xor(A, off, 64);
        B += __shfl_xor(B, off, 64);
    }
    float C = Wi[0] + b[i];

    float u = e[n];
    float s = scale[0];

    // p = u^(i+1)  (block-uniform trip count, no divergence)
    float p = u;
    for (int k = 0; k < i; ++k) p *= u;

    float sp = s * p;
    // exp(-0.5*(sp*j)^2) = exp2(c * j^2), c = -0.5*log2(e)*sp^2
    float c = -0.5f * 1.44269504088896340736f * sp * sp;

    float acc = 0.0f;
    #pragma unroll
    for (int j = 1; j <= 64; ++j) {
        acc += exp2f(c * (float)(j * j));   // j*j is a compile-time constant
    }
    float gw = acc * (1.0f / 64.0f);

    out[gid] = C + gw * (A + 2.0f * sp * B);
}

extern "C" void kernel_launch(void* const* d_in, const int* in_sizes, int n_in,
                              void* d_out, int out_size, void* d_ws, size_t ws_size,
                              hipStream_t stream) {
    const float* e     = (const float*)d_in[0];
    const float* W     = (const float*)d_in[1];
    const float* b     = (const float*)d_in[2];
    const float* scale = (const float*)d_in[3];
    float* out = (float*)d_out;

    int total = KK * NN;   // 524288 outputs, one thread each -> 2048 blocks
    hermite_fused_kernel<<<total / 256, 256, 0, stream>>>(e, W, b, scale, out);
}

// Round 5
// 10.052 us; speedup vs baseline: 1.7368x; 1.3130x over previous
//
#include <hip/hip_runtime.h>

#define NN 65536
#define KK 8

// out[i*NN+n] = C_i + gw * (A_i + 2*s*e[n]^(i+1)*B_i)
//   A_i = sum_j W[i,1+j] (j=0..63), B_i = sum_j (j+1)*W[i,65+j], C_i = W[i,0]+b[i]
//   gw  = (1/64) * sum_{j=1..64} exp2(c*j^2), c = -0.5*log2e*(s*e^(i+1))^2
// Only H0=1 and H1=2x survive bases[:, :HIDDEN] in the reference.
// The exp2 sum uses the recurrence t_{j+1}=t_j*r_j, r_{j+1}=r_j*q:
// one hardware exp2 instead of 64 (trans-pipe -> VALU trade).
__global__ void __launch_bounds__(256)
hermite_fused_kernel(const float* __restrict__ e,
                     const float* __restrict__ W,
                     const float* __restrict__ b,
                     const float* __restrict__ scale,
                     float* __restrict__ out) {
    int gid  = blockIdx.x * 256 + threadIdx.x;
    int i    = gid >> 16;          // output row 0..7 (block-uniform)
    int n    = gid & (NN - 1);     // element index
    int lane = threadIdx.x & 63;

    // Per-wave recompute of A_i, B_i (butterfly: every lane ends with the sum).
    // W rows are L2-resident broadcasts (256 blocks share each i).
    const float* Wi = W + i * 129;
    float A = Wi[1 + lane];
    float B = (float)(lane + 1) * Wi[65 + lane];
    #pragma unroll
    for (int off = 1; off < 64; off <<= 1) {
        A += __shfl_xor(A, off, 64);
        B += __shfl_xor(B, off, 64);
    }
    float C = Wi[0] + b[i];

    float u = e[n];
    float s = scale[0];

    // p = u^(i+1)  (block-uniform trip count, no divergence)
    float p = u;
    for (int k = 0; k < i; ++k) p *= u;

    float sp = s * p;
    float c  = -0.5f * 1.44269504088896340736f * sp * sp;   // exp(-x) -> exp2

    // t_j = exp2(c*j^2); t_1 = exp2(c); ratio_j = t_{j+1}/t_j = exp2(c(2j+1));
    // ratio_1 = exp2(3c) = t1*q; ratio_{j+1} = ratio_j * q, q = exp2(2c).
    float t1    = exp2f(c);
    float q     = t1 * t1;
    float term  = t1;
    float ratio = t1 * q;
    float acc   = term;
    #pragma unroll
    for (int j = 2; j <= 64; ++j) {
        term  *= ratio;
        ratio *= q;
        acc   += term;
    }
    float gw = acc * (1.0f / 64.0f);

    out[gid] = C + gw * (A + 2.0f * sp * B);
}

extern "C" void kernel_launch(void* const* d_in, const int* in_sizes, int n_in,
                              void* d_out, int out_size, void* d_ws, size_t ws_size,
                              hipStream_t stream) {
    const float* e     = (const float*)d_in[0];
    const float* W     = (const float*)d_in[1];
    const float* b     = (const float*)d_in[2];
    const float* scale = (const float*)d_in[3];
    float* out = (float*)d_out;

    int total = KK * NN;   // 524288 outputs, one thread each -> 2048 blocks
    hermite_fused_kernel<<<total / 256, 256, 0, stream>>>(e, W, b, scale, out);
}

// Round 7
// 9.769 us; speedup vs baseline: 1.7872x; 1.0290x over previous
//
#include <hip/hip_runtime.h>

#define NN 65536
#define KK 8

// out[i*NN+n] = C_i + gw * (A_i + 2*s*e[n]^(i+1)*B_i)
//   A_i = sum_j W[i,1+j] (j=0..63), B_i = sum_j (j+1)*W[i,65+j], C_i = W[i,0]+b[i]
//   gw  = (1/64) * sum_{j=1..64} exp2(c*j^2), c = -0.5*log2e*(s*e^(i+1))^2
// Only H0=1 and H1=2x survive bases[:, :HIDDEN] in the reference.
// The exp2 sum is computed as TWO independent 32-term multiplicative
// recurrences (j=1..32 and j=33..64) so the compiler can SLP-pack the
// identically-shaped mul/add pairs into v_pk_mul_f32/v_pk_add_f32
// (double-rate f32) and the dep chain is halved.
__global__ void __launch_bounds__(256)
hermite_fused_kernel(const float* __restrict__ e,
                     const float* __restrict__ W,
                     const float* __restrict__ b,
                     const float* __restrict__ scale,
                     float* __restrict__ out) {
    int gid  = blockIdx.x * 256 + threadIdx.x;
    int i    = gid >> 16;          // output row 0..7 (block-uniform)
    int n    = gid & (NN - 1);     // element index
    int lane = threadIdx.x & 63;

    // Per-wave recompute of A_i, B_i (butterfly: every lane ends with the sum).
    // W rows are L2-resident broadcasts (256 blocks share each i).
    const float* Wi = W + i * 129;
    float A = Wi[1 + lane];
    float B = (float)(lane + 1) * Wi[65 + lane];
    #pragma unroll
    for (int off = 1; off < 64; off <<= 1) {
        A += __shfl_xor(A, off, 64);
        B += __shfl_xor(B, off, 64);
    }
    float C = Wi[0] + b[i];

    float u = e[n];
    float s = scale[0];

    // p = u^(i+1)  (block-uniform trip count, no divergence)
    float p = u;
    for (int k = 0; k < i; ++k) p *= u;

    float sp = s * p;
    float c  = -0.5f * 1.44269504088896340736f * sp * sp;   // exp(-x) -> exp2

    // t_j = exp2(c*j^2), ratio_j = t_{j+1}/t_j = exp2(c(2j+1)), q = exp2(2c).
    // Chain A: j=1..32 start t1=exp2(c),      r=exp2(3c)
    // Chain B: j=33..64 start t33=exp2(1089c), r=exp2(67c)
    float tA = exp2f(c);
    float q  = tA * tA;
    float rA = tA * q;
    float tB = exp2f(1089.0f * c);
    float rB = exp2f(67.0f * c);
    float accA = tA;
    float accB = tB;
    #pragma unroll
    for (int m = 2; m <= 32; ++m) {
        tA *= rA;  tB *= rB;
        rA *= q;   rB *= q;
        accA += tA; accB += tB;
    }
    float gw = (accA + accB) * (1.0f / 64.0f);

    out[gid] = C + gw * (A + 2.0f * sp * B);
}

extern "C" void kernel_launch(void* const* d_in, const int* in_sizes, int n_in,
                              void* d_out, int out_size, void* d_ws, size_t ws_size,
                              hipStream_t stream) {
    const float* e     = (const float*)d_in[0];
    const float* W     = (const float*)d_in[1];
    const float* b     = (const float*)d_in[2];
    const float* scale = (const float*)d_in[3];
    float* out = (float*)d_out;

    int total = KK * NN;   // 524288 outputs, one thread each -> 2048 blocks
    hermite_fused_kernel<<<total / 256, 256, 0, stream>>>(e, W, b, scale, out);
}